// Round 8
// baseline (647.931 us; speedup 1.0000x reference)
//
#include <hip/hip_runtime.h>
#include <stdint.h>

// DBSCAN, N=16384 points in R^3, eps=0.2, minPts=10.
//
// R8 (4 launches): replace the 134M-pair N^2 pass with a uniform grid
// (cell=0.25, 36^3) -> ~2.5M candidate pairs (~50x less work), and cut
// launches 6->4 (measured ~12us fixed gap per launch).
//   k_prep  : ONE 1024-thread block: parent=i, counters, hist zero,
//             histogram, exclusive scan (in-block), scatter points into
//             cell-sorted float4 (x,y,z,sq) + orig-index arrays.
//   k_deg   : per sorted point: exact neighbor count over 9 x-row ranges
//             (3x3x3 stencil, x-dim merged) -> deg[orig] (no atomics).
//   k_build : per sorted point, deg complete: classify each pair (j<i):
//             core-core -> fire-and-forget global atomicMin hook + cclist;
//             mixed -> mbuf. Block-scan reservation, 2 global atomics/block.
//   k_finish: ONE block: parent->LDS (border=BIG), wavefront compress,
//             contraction rounds over cclist to exact fixpoint, then ranks/
//             border labels/output ALL in LDS: roots re-encoded in-place as
//             ENCB+rank, cores remapped to their root's code, borders take
//             atomicMin of neighbor codes via mbuf (rank is monotone in root
//             index, so min-code == min-root == reference semantics).
//
// Numerics replicate the reference EXACTLY in fp32 (absmax=0 in R1-R7):
//   sq  = (x*x + y*y) + z*z               (left-to-right)
//   dot = fma(z,z', fma(y,y', x*x'))      (BLAS k-ordered FMA chain)
//   d2  = (sq_i + sq_j) - 2.0f*dot ; adj = d2 < 0.04f
// Grid completeness: |dx|<=0.2+4e-6 per dim for any accepted pair; cell
// width 0.25 guarantees +-1 cell -> the 3^3 stencil covers all pairs.

#define N_PTS   16384
#define EPS2    0.04f
#define MINPTS  10
#define GD      36
#define NCELLS  (GD * GD * GD)          // 46656
#define CS      46                      // prep scan: cells per thread (1024*46 >= NCELLS)
#define CCAP    196608                  // core-core edge list capacity
#define MCAP    65536                   // mixed edge list capacity
#define BCAP    131072                  // contraction ping-pong capacity
#define NCC     1024
#define CHUNK   (N_PTS / NCC)           // 16
#define BIG     N_PTS                   // border sentinel during contraction
#define ENCB    16400                   // cluster-code base (> BIG)
#define HUGEV   (1 << 29)               // noise sentinel after re-encoding

__device__ __forceinline__ float sqsum(float x, float y, float z) {
    return __fadd_rn(__fadd_rn(__fmul_rn(x, x), __fmul_rn(y, y)), __fmul_rn(z, z));
}
__device__ __forceinline__ float dist2(float px, float py, float pz, float sqi, float4 q) {
    float dot = __fmaf_rn(pz, q.z, __fmaf_rn(py, q.y, __fmul_rn(px, q.x)));
    return __fsub_rn(__fadd_rn(sqi, q.w), __fmul_rn(2.0f, dot));
}
__device__ __forceinline__ int cellc(float v) {
    int c = (int)floorf((v + 4.5f) * 4.0f);
    return min(max(c, 0), GD - 1);
}
__device__ __forceinline__ int pload(const int* p) {
    return __hip_atomic_load(p, __ATOMIC_RELAXED, __HIP_MEMORY_SCOPE_AGENT);
}

// ---------------------------------------------------------------------------
__global__ void __launch_bounds__(1024)
k_prep(const float* __restrict__ pts, int* __restrict__ hist,
       int* __restrict__ cellstart, int* __restrict__ cellcur,
       int* __restrict__ parent, int* __restrict__ cnts,
       float4* __restrict__ sorted, int* __restrict__ sidx) {
    const int tid = threadIdx.x;
    for (int c = tid; c < NCELLS; c += 1024) hist[c] = 0;
    for (int i = tid; i < N_PTS; i += 1024) parent[i] = i;
    if (tid < 8) cnts[tid] = 0;
    __syncthreads();
    for (int i = tid; i < N_PTS; i += 1024) {
        float x = pts[3 * i], y = pts[3 * i + 1], z = pts[3 * i + 2];
        int c = (cellc(z) * GD + cellc(y)) * GD + cellc(x);
        atomicAdd(&hist[c], 1);
    }
    __syncthreads();
    // exclusive scan of hist -> cellstart (+ cursor copy)
    int loc[CS]; int s = 0; const int base = tid * CS;
#pragma unroll
    for (int k = 0; k < CS; ++k) {
        int c = base + k; int v = (c < NCELLS) ? hist[c] : 0;
        loc[k] = v; s += v;
    }
    __shared__ int wsum[16];
    const int lane = tid & 63, wv = tid >> 6;
    int incl = s;
#pragma unroll
    for (int d = 1; d < 64; d <<= 1) { int t = __shfl_up(incl, d, 64); if (lane >= d) incl += t; }
    if (lane == 63) wsum[wv] = incl;
    __syncthreads();
    int wbase = 0;
    for (int w = 0; w < wv; ++w) wbase += wsum[w];
    int ex = wbase + incl - s;
#pragma unroll
    for (int k = 0; k < CS; ++k) {
        int c = base + k;
        if (c < NCELLS) { cellstart[c] = ex; cellcur[c] = ex; ex += loc[k]; }
    }
    if (tid == 1023) cellstart[NCELLS] = ex;   // == N (tid 1023's cells are all past NCELLS)
    __syncthreads();
    // scatter into cell order
    for (int i = tid; i < N_PTS; i += 1024) {
        float x = pts[3 * i], y = pts[3 * i + 1], z = pts[3 * i + 2];
        int c = (cellc(z) * GD + cellc(y)) * GD + cellc(x);
        int slot = atomicAdd(&cellcur[c], 1);
        sorted[slot] = make_float4(x, y, z, sqsum(x, y, z));
        sidx[slot] = i;
    }
}

// ---------------------------------------------------------------------------
__global__ void k_deg(const float4* __restrict__ sorted, const int* __restrict__ sidx,
                      const int* __restrict__ cellstart, int* __restrict__ deg) {
    const int s = blockIdx.x * 256 + threadIdx.x;
    float4 me = sorted[s];
    const int cx = cellc(me.x), cy = cellc(me.y), cz = cellc(me.z);
    int nb = 0;
    for (int dz = -1; dz <= 1; ++dz) {
        int z = cz + dz; if ((unsigned)z >= GD) continue;
        for (int dy = -1; dy <= 1; ++dy) {
            int y = cy + dy; if ((unsigned)y >= GD) continue;
            int row = (z * GD + y) * GD;
            int a = cellstart[row + max(cx - 1, 0)];
            int b = cellstart[row + min(cx + 1, GD - 1) + 1];
            for (int k = a; k < b; ++k) {
                if (k == s) continue;
                float4 q = sorted[k];
                float d2 = dist2(me.x, me.y, me.z, me.w, q);
                nb += (d2 < EPS2) ? 1 : 0;
            }
        }
    }
    deg[sidx[s]] = nb + 1;   // +1: self (d2(p,p) ~ 1e-6 < eps2 always)
}

// ---------------------------------------------------------------------------
__global__ void k_build(const float4* __restrict__ sorted, const int* __restrict__ sidx,
                        const int* __restrict__ cellstart, const int* __restrict__ deg,
                        int* __restrict__ parent,
                        uint32_t* __restrict__ cclist, int* __restrict__ ccnt,
                        uint32_t* __restrict__ mbuf, int* __restrict__ mcnt) {
    const int s = blockIdx.x * 256 + threadIdx.x;
    const int tid = threadIdx.x, lane = tid & 63, wv = tid >> 6;
    float4 me = sorted[s];
    const int io = sidx[s];
    const bool ci = deg[io] >= MINPTS;
    const int cx = cellc(me.x), cy = cellc(me.y), cz = cellc(me.z);
    // pass 1: count cc / mixed pairs owned by this thread (jo < io)
    int ncc = 0, nmx = 0;
    for (int dz = -1; dz <= 1; ++dz) {
        int z = cz + dz; if ((unsigned)z >= GD) continue;
        for (int dy = -1; dy <= 1; ++dy) {
            int y = cy + dy; if ((unsigned)y >= GD) continue;
            int row = (z * GD + y) * GD;
            int a = cellstart[row + max(cx - 1, 0)];
            int b = cellstart[row + min(cx + 1, GD - 1) + 1];
            for (int k = a; k < b; ++k) {
                if (k == s) continue;
                float4 q = sorted[k];
                float d2 = dist2(me.x, me.y, me.z, me.w, q);
                if (d2 < EPS2) {
                    int jo = sidx[k];
                    if (jo < io) {
                        bool cj = deg[jo] >= MINPTS;
                        if (ci && cj) ++ncc; else if (ci != cj) ++nmx;
                    }
                }
            }
        }
    }
    // block-level reservation: 2 global atomics per block
    __shared__ int swc[4], swm[4], sbc, sbm;
    int ic = ncc, im = nmx;
#pragma unroll
    for (int d = 1; d < 64; d <<= 1) {
        int t = __shfl_up(ic, d, 64); if (lane >= d) ic += t;
        int u = __shfl_up(im, d, 64); if (lane >= d) im += u;
    }
    if (lane == 63) { swc[wv] = ic; swm[wv] = im; }
    __syncthreads();
    if (tid == 0) {
        int tc = 0, tm = 0;
        for (int w = 0; w < 4; ++w) {
            int a = swc[w]; swc[w] = tc; tc += a;
            int b = swm[w]; swm[w] = tm; tm += b;
        }
        sbc = atomicAdd(ccnt, tc);
        sbm = atomicAdd(mcnt, tm);
    }
    __syncthreads();
    int offc = sbc + swc[wv] + ic - ncc;
    int offm = sbm + swm[wv] + im - nmx;
    // pass 2: identical iteration -> write + hook
    for (int dz = -1; dz <= 1; ++dz) {
        int z = cz + dz; if ((unsigned)z >= GD) continue;
        for (int dy = -1; dy <= 1; ++dy) {
            int y = cy + dy; if ((unsigned)y >= GD) continue;
            int row = (z * GD + y) * GD;
            int a = cellstart[row + max(cx - 1, 0)];
            int b = cellstart[row + min(cx + 1, GD - 1) + 1];
            for (int k = a; k < b; ++k) {
                if (k == s) continue;
                float4 q = sorted[k];
                float d2 = dist2(me.x, me.y, me.z, me.w, q);
                if (d2 < EPS2) {
                    int jo = sidx[k];
                    if (jo < io) {
                        bool cj = deg[jo] >= MINPTS;
                        if (ci && cj) {
                            atomicMin(&parent[io], jo);        // fire-and-forget hook
                            if (offc < CCAP) cclist[offc] = ((uint32_t)io << 14) | (uint32_t)jo;
                            ++offc;
                        } else if (ci != cj) {
                            uint32_t pk = ci ? (((uint32_t)io << 14) | (uint32_t)jo)
                                             : (((uint32_t)jo << 14) | (uint32_t)io); // core<<14|border
                            if (offm < MCAP) mbuf[offm] = pk;
                            ++offm;
                        }
                    }
                }
            }
        }
    }
}

// ---------------------------------------------------------------------------
__global__ void __launch_bounds__(NCC)
k_finish(const int* __restrict__ parent_g, const int* __restrict__ deg,
         const uint32_t* __restrict__ cclist, const int* __restrict__ ccnt,
         const uint32_t* __restrict__ mbuf, const int* __restrict__ mcnt,
         uint32_t* __restrict__ bufA, uint32_t* __restrict__ bufB,
         float* __restrict__ out) {
    __shared__ int parent[N_PTS];                   // 64 KB
    __shared__ int s_nout;
    __shared__ int wsum[16];
    const int tid = threadIdx.x, lane = tid & 63, wv = tid >> 6;
    const uint64_t lane_lt = (1ull << lane) - 1;

#pragma unroll
    for (int k = 0; k < CHUNK; ++k) {
        int x = k * NCC + tid;                      // coalesced
        parent[x] = (deg[x] >= MINPTS) ? parent_g[x] : BIG;
    }
    __syncthreads();
    // initial compress: wavefront chase, 16 independent streams per thread
    {
        int v[CHUNK];
#pragma unroll
        for (int k = 0; k < CHUNK; ++k) v[k] = parent[k * NCC + tid];
        bool any = true;
        while (any) {
            any = false;
#pragma unroll
            for (int k = 0; k < CHUNK; ++k) {
                if (v[k] < BIG) {
                    int q = parent[v[k]];
                    if (q != v[k]) { v[k] = q; any = true; }
                }
            }
        }
#pragma unroll
        for (int k = 0; k < CHUNK; ++k)
            if (v[k] < BIG) parent[k * NCC + tid] = v[k];
    }
    __syncthreads();

    // contraction rounds to exact fixpoint (round 0 scans the full cclist)
    int n_in = min(pload(ccnt), CCAP);
    const uint32_t* cur = cclist;
    for (int r = 0; r < 24; ++r) {
        uint32_t* nxt = (r & 1) ? bufB : bufA;
        if (tid == 0) s_nout = 0;
        __syncthreads();
        const int n4 = (n_in + 3) & ~3;
        for (int bb = tid * 4; bb < n4; bb += NCC * 4) {
            uint4 pk = *(const uint4*)(cur + bb);
#pragma unroll
            for (int k = 0; k < 4; ++k) {
                uint32_t p = (k == 0) ? pk.x : (k == 1) ? pk.y : (k == 2) ? pk.z : pk.w;
                bool valid = (bb + k) < n_in;
                int ri = 0, rj = 0;
                if (valid) {
                    ri = parent[(int)(p >> 14)];
                    rj = parent[(int)(p & (N_PTS - 1))];
                }
                bool live = valid && (ri != rj);
                int lo = min(ri, rj), hi = max(ri, rj);
                if (live) atomicMin(&parent[hi], lo);        // LDS fire-and-forget
                uint64_t m = __ballot(live);
                if (m) {
                    int ldr = (int)__ffsll((unsigned long long)m) - 1;
                    int base = 0;
                    if (lane == ldr) base = atomicAdd(&s_nout, (int)__popcll(m));
                    base = __shfl(base, ldr);
                    if (live) {
                        int pos = base + (int)__popcll(m & lane_lt);
                        if (pos < BCAP) nxt[pos] = ((uint32_t)hi << 14) | (uint32_t)lo;
                    }
                }
            }
        }
        __syncthreads();
        int v[CHUNK];
#pragma unroll
        for (int k = 0; k < CHUNK; ++k) v[k] = parent[k * NCC + tid];
        bool any = true;
        while (any) {
            any = false;
#pragma unroll
            for (int k = 0; k < CHUNK; ++k) {
                if (v[k] < BIG) {
                    int q = parent[v[k]];
                    if (q != v[k]) { v[k] = q; any = true; }
                }
            }
        }
#pragma unroll
        for (int k = 0; k < CHUNK; ++k)
            if (v[k] < BIG) parent[k * NCC + tid] = v[k];
        __syncthreads();
        if (s_nout == 0) break;                     // uniform
        n_in = min(s_nout, BCAP);
        cur = nxt;
    }

    // D1: rank roots in scan order; re-encode root slots in place as ENCB+rank
    const int bn = tid * CHUNK;
    int fl[CHUNK]; int s = 0;
#pragma unroll
    for (int k = 0; k < CHUNK; ++k) {
        fl[k] = (parent[bn + k] == bn + k) ? 1 : 0;   // borders hold BIG != index
        s += fl[k];
    }
    int incl = s;
#pragma unroll
    for (int d = 1; d < 64; d <<= 1) { int t = __shfl_up(incl, d, 64); if (lane >= d) incl += t; }
    if (lane == 63) wsum[wv] = incl;
    __syncthreads();
    int wbase = 0;
    for (int w = 0; w < wv; ++w) wbase += wsum[w];
    int c = wbase + incl - s;
#pragma unroll
    for (int k = 0; k < CHUNK; ++k)
        if (fl[k]) parent[bn + k] = ENCB + (c++);
    __syncthreads();
    // D2: non-root cores -> their root's code; borders -> HUGE sentinel
#pragma unroll
    for (int k = 0; k < CHUNK; ++k) {
        int x = k * NCC + tid;
        int p = parent[x];
        if (p < BIG) parent[x] = parent[p];         // root slots are stable (>= ENCB)
        else if (p == BIG) parent[x] = HUGEV;
    }
    __syncthreads();
    // C: border labels = min neighbor-cluster code (rank monotone in root => min ok)
    int nm = min(pload(mcnt), MCAP);
    for (int e = tid; e < nm; e += NCC) {
        uint32_t p = mbuf[e];
        int cc = (int)(p >> 14), bb = (int)(p & (N_PTS - 1));
        atomicMin(&parent[bb], parent[cc]);         // LDS
    }
    __syncthreads();
    // E: labels
#pragma unroll
    for (int k = 0; k < CHUNK; ++k) {
        int x = k * NCC + tid;                      // coalesced store
        int v = parent[x];
        out[x] = (v < HUGEV) ? (float)(v - ENCB) : -1.0f;
    }
}

// ---------------------------------------------------------------------------
extern "C" void kernel_launch(void* const* d_in, const int* in_sizes, int n_in,
                              void* d_out, int out_size, void* d_ws, size_t ws_size,
                              hipStream_t stream) {
    (void)in_sizes; (void)n_in; (void)out_size; (void)ws_size;
    const float* pts = (const float*)d_in[0];
    float* out = (float*)d_out;

    // ws layout (words; every offset is a multiple of 16 -> uint4/float4 safe)
    int* ib = (int*)d_ws;
    int*      hist      = ib;                               // 46656
    int*      cellstart = hist + NCELLS;                    // 46672 (NCELLS+1 padded)
    int*      cellcur   = cellstart + 46672;                // 46656
    float4*   sorted    = (float4*)(cellcur + NCELLS);      // 65536 words
    int*      sidx      = (int*)(sorted + N_PTS);           // 16384
    int*      deg       = sidx + N_PTS;                     // 16384
    int*      parent    = deg + N_PTS;                      // 16384
    int*      cnts      = parent + N_PTS;                   // 64
    int*      ccnt = cnts + 0, *mcnt = cnts + 1;
    uint32_t* cclist    = (uint32_t*)(cnts + 64);           // 196608
    uint32_t* mbuf      = cclist + CCAP;                    // 65536
    uint32_t* bufA      = mbuf + MCAP;                      // 131072
    uint32_t* bufB      = bufA + BCAP;                      // 131072  (~3.05 MB total)

    k_prep  <<<dim3(1),  dim3(1024), 0, stream>>>(pts, hist, cellstart, cellcur,
                                                  parent, cnts, sorted, sidx);
    k_deg   <<<dim3(64), dim3(256),  0, stream>>>(sorted, sidx, cellstart, deg);
    k_build <<<dim3(64), dim3(256),  0, stream>>>(sorted, sidx, cellstart, deg,
                                                  parent, cclist, ccnt, mbuf, mcnt);
    k_finish<<<dim3(1),  dim3(1024), 0, stream>>>(parent, deg, cclist, ccnt,
                                                  mbuf, mcnt, bufA, bufB, out);
}